// Round 1
// baseline (489.638 us; speedup 1.0000x reference)
//
#include <hip/hip_runtime.h>

// Problem constants (match the reference).
#define NB 128
#define HH 512
#define WW 512
#define HW (HH * WW)

constexpr float EPS_F = 1e-6f;
constexpr int IGNORE_V = -255;

constexpr int BPR = 32;                       // blocks per batch row
constexpr int TPB = 256;                      // threads per block
constexpr int EPB = HW / BPR;                 // 8192 elements per block
constexpr int F4_PER_THREAD = EPB / (TPB * 4); // 8 float4 per thread

// ---------------------------------------------------------------------------
// Pass 1: per-row partial sums of (cam + eps) AND fill output with IGNORE.
// One block handles EPB contiguous elements of one row. Deterministic: each
// block writes its own partial slot (no atomics).
// ---------------------------------------------------------------------------
__global__ __launch_bounds__(TPB) void k_sum_fill(const float* __restrict__ cam,
                                                  int* __restrict__ out,
                                                  float* __restrict__ partial) {
    const int b = blockIdx.y;
    const int chunk = blockIdx.x;
    const long base = (long)b * HW + (long)chunk * EPB;
    const float4* c4 = (const float4*)(cam + base);
    int4* o4 = (int4*)(out + base);
    const int t = threadIdx.x;
    const int4 fill = make_int4(IGNORE_V, IGNORE_V, IGNORE_V, IGNORE_V);

    float s = 0.f;
#pragma unroll
    for (int i = 0; i < F4_PER_THREAD; ++i) {
        float4 v = c4[t + i * TPB];
        s += (v.x + EPS_F) + (v.y + EPS_F) + (v.z + EPS_F) + (v.w + EPS_F);
        o4[t + i * TPB] = fill;
    }
    // wave64 shuffle reduce
#pragma unroll
    for (int off = 32; off > 0; off >>= 1) s += __shfl_down(s, off, 64);
    __shared__ float ls[TPB / 64];
    if ((t & 63) == 0) ls[t >> 6] = s;
    __syncthreads();
    if (t == 0) {
        float tot = 0.f;
#pragma unroll
        for (int w = 0; w < TPB / 64; ++w) tot += ls[w];
        partial[b * BPR + chunk] = tot;
    }
}

// Monotone packing: larger float => larger key; equal float => lower index wins
// (matches top_k first-occurrence tie-break).
__device__ inline unsigned long long pack_key(float f, unsigned idx) {
    unsigned bits = __float_as_uint(f);
    bits ^= (bits & 0x80000000u) ? 0xFFFFFFFFu : 0x80000000u;
    return ((unsigned long long)bits << 32) | (unsigned)(~idx);
}

// ---------------------------------------------------------------------------
// Pass 2: both argmaxes. Each block reduces its chunk and writes one packed
// candidate per row per mask (deterministic, no atomics).
// ---------------------------------------------------------------------------
__global__ __launch_bounds__(TPB) void k_argmax(const float* __restrict__ cam,
                                                const float* __restrict__ ufg,
                                                const float* __restrict__ ubg,
                                                const float* __restrict__ partial,
                                                unsigned long long* __restrict__ bestFg,
                                                unsigned long long* __restrict__ bestBg) {
    const int b = blockIdx.y;
    const int chunk = blockIdx.x;
    const int t = threadIdx.x;

    // Row sum (uniform across the block; scalarizes to s_loads).
    float S = 0.f;
    for (int i = 0; i < BPR; ++i) S += partial[b * BPR + i];

    const long base = (long)b * HW + (long)chunk * EPB;
    const float4* c4 = (const float4*)(cam + base);
    const float4* f4 = (const float4*)(ufg + base);
    const float4* g4 = (const float4*)(ubg + base);

    unsigned long long bf = 0ull, bb = 0ull;
#pragma unroll
    for (int i = 0; i < F4_PER_THREAD; ++i) {
        float4 v = c4[t + i * TPB];
        float4 uf = f4[t + i * TPB];
        float4 ub = g4[t + i * TPB];
        const unsigned idx0 = (unsigned)(chunk * EPB) + (unsigned)((t + i * TPB) * 4);
        float vv[4] = {v.x, v.y, v.z, v.w};
        float uu[4] = {uf.x, uf.y, uf.z, uf.w};
        float wwn[4] = {ub.x, ub.y, ub.z, ub.w};
#pragma unroll
        for (int j = 0; j < 4; ++j) {
            float p = (vv[j] + EPS_F) / S;                       // == reference p
            float gf = -logf(-logf(fmaxf(uu[j], 1e-12f)));       // gumbel(u_fg)
            float wf = logf(p) + gf;                             // log(p) + g
            float gb = -logf(-logf(fmaxf(wwn[j], 1e-12f)));      // gumbel(u_bg)
            float wb = log1pf(-p) + gb;                          // log1p(-p) + g
            unsigned long long kf = pack_key(wf, idx0 + j);
            unsigned long long kb = pack_key(wb, idx0 + j);
            bf = kf > bf ? kf : bf;
            bb = kb > bb ? kb : bb;
        }
    }
#pragma unroll
    for (int off = 32; off > 0; off >>= 1) {
        unsigned long long of = __shfl_down(bf, off, 64);
        unsigned long long ob = __shfl_down(bb, off, 64);
        bf = of > bf ? of : bf;
        bb = ob > bb ? ob : bb;
    }
    __shared__ unsigned long long lf[TPB / 64], lb[TPB / 64];
    if ((t & 63) == 0) { lf[t >> 6] = bf; lb[t >> 6] = bb; }
    __syncthreads();
    if (t == 0) {
        for (int w = 1; w < TPB / 64; ++w) {
            if (lf[w] > bf) bf = lf[w];
            if (lb[w] > bb) bb = lb[w];
        }
        bestFg[b * BPR + chunk] = bf;
        bestBg[b * BPR + chunk] = bb;
    }
}

// ---------------------------------------------------------------------------
// Pass 3: final 32-way max per row, then write the dilated 3x3 blocks with the
// overlap rule: fg\bg -> 1, bg\fg -> 0, intersection stays IGNORE.
// ---------------------------------------------------------------------------
__global__ void k_fixup(const unsigned long long* __restrict__ bestFg,
                        const unsigned long long* __restrict__ bestBg,
                        int* __restrict__ out) {
    const int b = threadIdx.x;
    if (b >= NB) return;
    unsigned long long bf = 0ull, bb = 0ull;
    for (int i = 0; i < BPR; ++i) {
        unsigned long long f = bestFg[b * BPR + i];
        unsigned long long g = bestBg[b * BPR + i];
        if (f > bf) bf = f;
        if (g > bb) bb = g;
    }
    const unsigned fidx = ~(unsigned)(bf & 0xFFFFFFFFull);
    const unsigned bidx = ~(unsigned)(bb & 0xFFFFFFFFull);
    const int fr = (int)(fidx / WW), fc = (int)(fidx % WW);
    const int br = (int)(bidx / WW), bc = (int)(bidx % WW);
    const long rb = (long)b * HW;

    for (int dr = -1; dr <= 1; ++dr) {
        for (int dc = -1; dc <= 1; ++dc) {
            int r = fr + dr, c = fc + dc;
            if (r >= 0 && r < HH && c >= 0 && c < WW) {
                bool inBg = (r >= br - 1 && r <= br + 1 && c >= bc - 1 && c <= bc + 1);
                if (!inBg) out[rb + (long)r * WW + c] = 1;
            }
            r = br + dr; c = bc + dc;
            if (r >= 0 && r < HH && c >= 0 && c < WW) {
                bool inFg = (r >= fr - 1 && r <= fr + 1 && c >= fc - 1 && c <= fc + 1);
                if (!inFg) out[rb + (long)r * WW + c] = 0;
            }
        }
    }
}

extern "C" void kernel_launch(void* const* d_in, const int* in_sizes, int n_in,
                              void* d_out, int out_size, void* d_ws, size_t ws_size,
                              hipStream_t stream) {
    const float* cam = (const float*)d_in[0];   // x: [128,1,512,512] f32
    const float* ufg = (const float*)d_in[1];   // u_fg: [128, HW] f32
    const float* ubg = (const float*)d_in[2];   // u_bg: [128, HW] f32
    int* out = (int*)d_out;                     // int32 [128,512,512]

    // Workspace layout (all fully written before read; no init needed):
    //   [0,        16384)  float  partial[NB*BPR]
    //   [16384,    49152)  ull    bestFg[NB*BPR]
    //   [49152,    81920)  ull    bestBg[NB*BPR]
    float* partial = (float*)d_ws;
    unsigned long long* bestFg = (unsigned long long*)((char*)d_ws + 16384);
    unsigned long long* bestBg = (unsigned long long*)((char*)d_ws + 49152);

    dim3 grid(BPR, NB);
    k_sum_fill<<<grid, TPB, 0, stream>>>(cam, out, partial);
    k_argmax<<<grid, TPB, 0, stream>>>(cam, ufg, ubg, partial, bestFg, bestBg);
    k_fixup<<<1, 128, 0, stream>>>(bestFg, bestBg, out);
}

// Round 2
// 426.879 us; speedup vs baseline: 1.1470x; 1.1470x over previous
//
#include <hip/hip_runtime.h>

// Problem constants (match the reference).
#define NB 128
#define HH 512
#define WW 512
#define HW (HH * WW)

constexpr float EPS_F = 1e-6f;
constexpr int IGNORE_V = -255;

constexpr int BPR = 32;                        // blocks per batch row
constexpr int TPB = 256;                       // threads per block
constexpr int EPB = HW / BPR;                  // 8192 elements per block
constexpr int F4_PER_THREAD = EPB / (TPB * 4); // 8 float4 per thread

// Monotone packing: larger float => larger key; equal float => lower index wins
// (matches top_k first-occurrence tie-break). Inputs here are >= 0 or +inf.
__device__ inline unsigned long long pack_key(float f, unsigned idx) {
    unsigned bits = __float_as_uint(f);
    bits ^= (bits & 0x80000000u) ? 0xFFFFFFFFu : 0x80000000u;
    return ((unsigned long long)bits << 32) | (unsigned)(~idx);
}

// ---------------------------------------------------------------------------
// Pass 1 (fused): per-row partial sums of (cam+eps), IGNORE-fill of out, and
// the FG Gumbel-argmax. Key algebra: argmax log(p)+(-log(-log u)) ==
// argmax (cam+eps)/(-log u) — S cancels, so fg needs no row sum.
// One block = one contiguous 8192-elem chunk of one row; deterministic
// per-block outputs (no atomics).
// ---------------------------------------------------------------------------
__global__ __launch_bounds__(TPB) void k_fg_sum_fill(const float* __restrict__ cam,
                                                     const float* __restrict__ ufg,
                                                     int* __restrict__ out,
                                                     float* __restrict__ partial,
                                                     unsigned long long* __restrict__ bestFg) {
    const int b = blockIdx.y;
    const int chunk = blockIdx.x;
    const long base = (long)b * HW + (long)chunk * EPB;
    const float4* c4 = (const float4*)(cam + base);
    const float4* f4 = (const float4*)(ufg + base);
    int4* o4 = (int4*)(out + base);
    const int t = threadIdx.x;
    const int4 fill = make_int4(IGNORE_V, IGNORE_V, IGNORE_V, IGNORE_V);

    float s = 0.f;
    unsigned long long bf = 0ull;
#pragma unroll
    for (int i = 0; i < F4_PER_THREAD; ++i) {
        float4 v = c4[t + i * TPB];
        float4 uf = f4[t + i * TPB];
        o4[t + i * TPB] = fill;
        const unsigned idx0 = (unsigned)(chunk * EPB) + (unsigned)((t + i * TPB) * 4);
        float vv[4] = {v.x, v.y, v.z, v.w};
        float uu[4] = {uf.x, uf.y, uf.z, uf.w};
#pragma unroll
        for (int j = 0; j < 4; ++j) {
            float a = vv[j] + EPS_F;
            s += a;
            float E = -logf(fmaxf(uu[j], 1e-12f));   // -log(u); E>=0, ==0 only if u==1
            unsigned long long kf = pack_key(a / E, idx0 + j);
            bf = kf > bf ? kf : bf;
        }
    }
    // wave64 reductions
#pragma unroll
    for (int off = 32; off > 0; off >>= 1) {
        s += __shfl_down(s, off, 64);
        unsigned long long of = __shfl_down(bf, off, 64);
        bf = of > bf ? of : bf;
    }
    __shared__ float ls[TPB / 64];
    __shared__ unsigned long long lf[TPB / 64];
    if ((t & 63) == 0) { ls[t >> 6] = s; lf[t >> 6] = bf; }
    __syncthreads();
    if (t == 0) {
        float tot = 0.f;
#pragma unroll
        for (int w = 0; w < TPB / 64; ++w) {
            tot += ls[w];
            if (lf[w] > bf) bf = lf[w];
        }
        partial[b * BPR + chunk] = tot;
        bestFg[b * BPR + chunk] = bf;
    }
}

// ---------------------------------------------------------------------------
// Pass 2: BG Gumbel-argmax. argmax log1p(-p)+(-log(-log u)) ==
// argmax (S - (cam+eps))/(-log u). cam should come from L2/L3 (just read).
// ---------------------------------------------------------------------------
__global__ __launch_bounds__(TPB) void k_bg(const float* __restrict__ cam,
                                            const float* __restrict__ ubg,
                                            const float* __restrict__ partial,
                                            unsigned long long* __restrict__ bestBg) {
    const int b = blockIdx.y;
    const int chunk = blockIdx.x;
    const int t = threadIdx.x;

    float S = 0.f;
    for (int i = 0; i < BPR; ++i) S += partial[b * BPR + i];

    const long base = (long)b * HW + (long)chunk * EPB;
    const float4* c4 = (const float4*)(cam + base);
    const float4* g4 = (const float4*)(ubg + base);

    unsigned long long bb = 0ull;
#pragma unroll
    for (int i = 0; i < F4_PER_THREAD; ++i) {
        float4 v = c4[t + i * TPB];
        float4 ub = g4[t + i * TPB];
        const unsigned idx0 = (unsigned)(chunk * EPB) + (unsigned)((t + i * TPB) * 4);
        float vv[4] = {v.x, v.y, v.z, v.w};
        float uu[4] = {ub.x, ub.y, ub.z, ub.w};
#pragma unroll
        for (int j = 0; j < 4; ++j) {
            float num = S - (vv[j] + EPS_F);         // same 6e-8 rel rounding class as ref's (1-p)
            float E = -logf(fmaxf(uu[j], 1e-12f));
            unsigned long long kb = pack_key(num / E, idx0 + j);
            bb = kb > bb ? kb : bb;
        }
    }
#pragma unroll
    for (int off = 32; off > 0; off >>= 1) {
        unsigned long long ob = __shfl_down(bb, off, 64);
        bb = ob > bb ? ob : bb;
    }
    __shared__ unsigned long long lb[TPB / 64];
    if ((t & 63) == 0) lb[t >> 6] = bb;
    __syncthreads();
    if (t == 0) {
        for (int w = 1; w < TPB / 64; ++w)
            if (lb[w] > bb) bb = lb[w];
        bestBg[b * BPR + chunk] = bb;
    }
}

// ---------------------------------------------------------------------------
// Pass 3: final 32-way max per row, then write the dilated 3x3 blocks with the
// overlap rule: fg\bg -> 1, bg\fg -> 0, intersection stays IGNORE.
// ---------------------------------------------------------------------------
__global__ void k_fixup(const unsigned long long* __restrict__ bestFg,
                        const unsigned long long* __restrict__ bestBg,
                        int* __restrict__ out) {
    const int b = threadIdx.x;
    if (b >= NB) return;
    unsigned long long bf = 0ull, bb = 0ull;
    for (int i = 0; i < BPR; ++i) {
        unsigned long long f = bestFg[b * BPR + i];
        unsigned long long g = bestBg[b * BPR + i];
        if (f > bf) bf = f;
        if (g > bb) bb = g;
    }
    const unsigned fidx = ~(unsigned)(bf & 0xFFFFFFFFull);
    const unsigned bidx = ~(unsigned)(bb & 0xFFFFFFFFull);
    const int fr = (int)(fidx / WW), fc = (int)(fidx % WW);
    const int br = (int)(bidx / WW), bc = (int)(bidx % WW);
    const long rb = (long)b * HW;

    for (int dr = -1; dr <= 1; ++dr) {
        for (int dc = -1; dc <= 1; ++dc) {
            int r = fr + dr, c = fc + dc;
            if (r >= 0 && r < HH && c >= 0 && c < WW) {
                bool inBg = (r >= br - 1 && r <= br + 1 && c >= bc - 1 && c <= bc + 1);
                if (!inBg) out[rb + (long)r * WW + c] = 1;
            }
            r = br + dr; c = bc + dc;
            if (r >= 0 && r < HH && c >= 0 && c < WW) {
                bool inFg = (r >= fr - 1 && r <= fr + 1 && c >= fc - 1 && c <= fc + 1);
                if (!inFg) out[rb + (long)r * WW + c] = 0;
            }
        }
    }
}

extern "C" void kernel_launch(void* const* d_in, const int* in_sizes, int n_in,
                              void* d_out, int out_size, void* d_ws, size_t ws_size,
                              hipStream_t stream) {
    const float* cam = (const float*)d_in[0];   // x: [128,1,512,512] f32
    const float* ufg = (const float*)d_in[1];   // u_fg: [128, HW] f32
    const float* ubg = (const float*)d_in[2];   // u_bg: [128, HW] f32
    int* out = (int*)d_out;                     // int32 [128,512,512]

    // Workspace layout (all fully written before read; no init needed):
    //   [0,        16384)  float  partial[NB*BPR]
    //   [16384,    49152)  ull    bestFg[NB*BPR]
    //   [49152,    81920)  ull    bestBg[NB*BPR]
    float* partial = (float*)d_ws;
    unsigned long long* bestFg = (unsigned long long*)((char*)d_ws + 16384);
    unsigned long long* bestBg = (unsigned long long*)((char*)d_ws + 49152);

    dim3 grid(BPR, NB);
    k_fg_sum_fill<<<grid, TPB, 0, stream>>>(cam, ufg, out, partial, bestFg);
    k_bg<<<grid, TPB, 0, stream>>>(cam, ubg, partial, bestBg);
    k_fixup<<<1, 128, 0, stream>>>(bestFg, bestBg, out);
}

// Round 4
// 414.103 us; speedup vs baseline: 1.1824x; 1.0309x over previous
//
#include <hip/hip_runtime.h>

// Problem constants (match the reference).
#define NB 128
#define HH 512
#define WW 512
#define HW (HH * WW)

constexpr float EPS_F = 1e-6f;
constexpr int IGNORE_V = -255;

constexpr int TPB = 256;               // threads per block
constexpr int G = 4;                   // float4 per prefetch group per stream
constexpr int NG = 4;                  // groups per thread
constexpr int F4T = G * NG;            // 16 float4 per thread
constexpr int EPB = TPB * F4T * 4;     // 16384 elements per block
constexpr int BPR = HW / EPB;          // 16 blocks per row (grid 16x128 = 2048 = 8/CU)

// Native Clang vector types — accepted by __builtin_nontemporal_load/store
// (HIP_vector_type float4/int4 are structs and are rejected).
typedef float floatx4 __attribute__((ext_vector_type(4)));
typedef int intx4 __attribute__((ext_vector_type(4)));

// Monotone packing: larger float => larger key; equal float => lower index wins
// (matches top_k first-occurrence tie-break). Inputs here are >= 0 finite.
__device__ inline unsigned long long pack_key(float f, unsigned idx) {
    unsigned bits = __float_as_uint(f);
    bits ^= (bits & 0x80000000u) ? 0xFFFFFFFFu : 0x80000000u;
    return ((unsigned long long)bits << 32) | (unsigned)(~idx);
}

// ---------------------------------------------------------------------------
// Pass 1 (fused): per-row partial sums of (cam+eps), IGNORE-fill of out, FG
// Gumbel-argmax (argmax log(p)+g == argmax (cam+eps)/(-log u); S cancels).
// Register double-buffered prefetch: 8 loads in flight sustained (16 at burst)
// to break the ~2-outstanding-load latency ceiling seen in R2 (VGPR=32).
// nt-loads on ufg and nt-stores on out keep cam resident in L3 for pass 2.
// ---------------------------------------------------------------------------
__global__ __launch_bounds__(TPB, 4) void k_fg_sum_fill(const float* __restrict__ cam,
                                                        const float* __restrict__ ufg,
                                                        int* __restrict__ out,
                                                        float* __restrict__ partial,
                                                        unsigned long long* __restrict__ bestFg) {
    const int b = blockIdx.y, chunk = blockIdx.x, t = threadIdx.x;
    const long base = (long)b * HW + (long)chunk * EPB;
    const floatx4* c4 = (const floatx4*)(cam + base);
    const floatx4* f4 = (const floatx4*)(ufg + base);
    intx4* o4 = (intx4*)(out + base);
    const intx4 fill = {IGNORE_V, IGNORE_V, IGNORE_V, IGNORE_V};

    floatx4 cb[2][G], ub[2][G];
#pragma unroll
    for (int k = 0; k < G; ++k) {
        cb[0][k] = c4[t + k * TPB];
        ub[0][k] = __builtin_nontemporal_load(&f4[t + k * TPB]);
    }

    float s = 0.f;
    unsigned long long bf = 0ull;
#pragma unroll
    for (int g = 0; g < NG; ++g) {
        const int cur = g & 1, nxt = cur ^ 1;
        if (g + 1 < NG) {
#pragma unroll
            for (int k = 0; k < G; ++k) {
                cb[nxt][k] = c4[t + ((g + 1) * G + k) * TPB];
                ub[nxt][k] = __builtin_nontemporal_load(&f4[t + ((g + 1) * G + k) * TPB]);
            }
        }
#pragma unroll
        for (int k = 0; k < G; ++k) {
            const int slot = g * G + k;
            __builtin_nontemporal_store(fill, &o4[t + slot * TPB]);
            floatx4 v = cb[cur][k];
            floatx4 uu = ub[cur][k];
            const unsigned idx0 = (unsigned)chunk * (unsigned)EPB + (unsigned)(t + slot * TPB) * 4u;
#pragma unroll
            for (int j = 0; j < 4; ++j) {
                float a = v[j] + EPS_F;
                s += a;
                float E = -logf(fmaxf(uu[j], 1e-12f));   // -log(u) > 0
                unsigned long long kf = pack_key(a / E, idx0 + j);
                bf = kf > bf ? kf : bf;
            }
        }
    }

    // wave64 reductions -> per-block outputs (deterministic, no atomics)
#pragma unroll
    for (int off = 32; off > 0; off >>= 1) {
        s += __shfl_down(s, off, 64);
        unsigned long long of = __shfl_down(bf, off, 64);
        bf = of > bf ? of : bf;
    }
    __shared__ float ls[TPB / 64];
    __shared__ unsigned long long lf[TPB / 64];
    if ((t & 63) == 0) { ls[t >> 6] = s; lf[t >> 6] = bf; }
    __syncthreads();
    if (t == 0) {
        float tot = 0.f;
#pragma unroll
        for (int w = 0; w < TPB / 64; ++w) {
            tot += ls[w];
            if (lf[w] > bf) bf = lf[w];
        }
        partial[b * BPR + chunk] = tot;
        bestFg[b * BPR + chunk] = bf;
    }
}

// ---------------------------------------------------------------------------
// Pass 2: BG Gumbel-argmax: argmax log1p(-p)+g == argmax (S-(cam+eps))/(-log u).
// cam re-read should hit L3 (protected by nt hints in pass 1). Everything here
// is read-once -> nt loads.
// ---------------------------------------------------------------------------
__global__ __launch_bounds__(TPB, 4) void k_bg(const float* __restrict__ cam,
                                               const float* __restrict__ ubg,
                                               const float* __restrict__ partial,
                                               unsigned long long* __restrict__ bestBg) {
    const int b = blockIdx.y, chunk = blockIdx.x, t = threadIdx.x;

    float S = 0.f;
    for (int i = 0; i < BPR; ++i) S += partial[b * BPR + i];

    const long base = (long)b * HW + (long)chunk * EPB;
    const floatx4* c4 = (const floatx4*)(cam + base);
    const floatx4* g4 = (const floatx4*)(ubg + base);

    floatx4 cb[2][G], ub[2][G];
#pragma unroll
    for (int k = 0; k < G; ++k) {
        cb[0][k] = __builtin_nontemporal_load(&c4[t + k * TPB]);
        ub[0][k] = __builtin_nontemporal_load(&g4[t + k * TPB]);
    }

    unsigned long long bb = 0ull;
#pragma unroll
    for (int g = 0; g < NG; ++g) {
        const int cur = g & 1, nxt = cur ^ 1;
        if (g + 1 < NG) {
#pragma unroll
            for (int k = 0; k < G; ++k) {
                cb[nxt][k] = __builtin_nontemporal_load(&c4[t + ((g + 1) * G + k) * TPB]);
                ub[nxt][k] = __builtin_nontemporal_load(&g4[t + ((g + 1) * G + k) * TPB]);
            }
        }
#pragma unroll
        for (int k = 0; k < G; ++k) {
            const int slot = g * G + k;
            floatx4 v = cb[cur][k];
            floatx4 uu = ub[cur][k];
            const unsigned idx0 = (unsigned)chunk * (unsigned)EPB + (unsigned)(t + slot * TPB) * 4u;
#pragma unroll
            for (int j = 0; j < 4; ++j) {
                float num = S - (v[j] + EPS_F);           // same rounding class as ref's (1-p)
                float E = -logf(fmaxf(uu[j], 1e-12f));
                unsigned long long kb = pack_key(num / E, idx0 + j);
                bb = kb > bb ? kb : bb;
            }
        }
    }

#pragma unroll
    for (int off = 32; off > 0; off >>= 1) {
        unsigned long long ob = __shfl_down(bb, off, 64);
        bb = ob > bb ? ob : bb;
    }
    __shared__ unsigned long long lb[TPB / 64];
    if ((t & 63) == 0) lb[t >> 6] = bb;
    __syncthreads();
    if (t == 0) {
        for (int w = 1; w < TPB / 64; ++w)
            if (lb[w] > bb) bb = lb[w];
        bestBg[b * BPR + chunk] = bb;
    }
}

// ---------------------------------------------------------------------------
// Pass 3: final per-row max over BPR candidates, then write the dilated 3x3
// blocks with the overlap rule: fg\bg -> 1, bg\fg -> 0, overlap stays IGNORE.
// ---------------------------------------------------------------------------
__global__ void k_fixup(const unsigned long long* __restrict__ bestFg,
                        const unsigned long long* __restrict__ bestBg,
                        int* __restrict__ out) {
    const int b = threadIdx.x;
    if (b >= NB) return;
    unsigned long long bf = 0ull, bb = 0ull;
    for (int i = 0; i < BPR; ++i) {
        unsigned long long f = bestFg[b * BPR + i];
        unsigned long long g = bestBg[b * BPR + i];
        if (f > bf) bf = f;
        if (g > bb) bb = g;
    }
    const unsigned fidx = ~(unsigned)(bf & 0xFFFFFFFFull);
    const unsigned bidx = ~(unsigned)(bb & 0xFFFFFFFFull);
    const int fr = (int)(fidx / WW), fc = (int)(fidx % WW);
    const int br = (int)(bidx / WW), bc = (int)(bidx % WW);
    const long rb = (long)b * HW;

    for (int dr = -1; dr <= 1; ++dr) {
        for (int dc = -1; dc <= 1; ++dc) {
            int r = fr + dr, c = fc + dc;
            if (r >= 0 && r < HH && c >= 0 && c < WW) {
                bool inBg = (r >= br - 1 && r <= br + 1 && c >= bc - 1 && c <= bc + 1);
                if (!inBg) out[rb + (long)r * WW + c] = 1;
            }
            r = br + dr; c = bc + dc;
            if (r >= 0 && r < HH && c >= 0 && c < WW) {
                bool inFg = (r >= fr - 1 && r <= fr + 1 && c >= fc - 1 && c <= fc + 1);
                if (!inFg) out[rb + (long)r * WW + c] = 0;
            }
        }
    }
}

extern "C" void kernel_launch(void* const* d_in, const int* in_sizes, int n_in,
                              void* d_out, int out_size, void* d_ws, size_t ws_size,
                              hipStream_t stream) {
    const float* cam = (const float*)d_in[0];   // x: [128,1,512,512] f32
    const float* ufg = (const float*)d_in[1];   // u_fg: [128, HW] f32
    const float* ubg = (const float*)d_in[2];   // u_bg: [128, HW] f32
    int* out = (int*)d_out;                     // int32 [128,512,512]

    // Workspace layout (fully written before read; no init needed):
    //   [0,     8192)  float  partial[NB*BPR]          (128*16*4 = 8 KB)
    //   [8192, 24576)  ull    bestFg[NB*BPR]           (16 KB)
    //   [24576,40960)  ull    bestBg[NB*BPR]           (16 KB)
    float* partial = (float*)d_ws;
    unsigned long long* bestFg = (unsigned long long*)((char*)d_ws + 8192);
    unsigned long long* bestBg = (unsigned long long*)((char*)d_ws + 24576);

    dim3 grid(BPR, NB);
    k_fg_sum_fill<<<grid, TPB, 0, stream>>>(cam, ufg, out, partial, bestFg);
    k_bg<<<grid, TPB, 0, stream>>>(cam, ubg, partial, bestBg);
    k_fixup<<<1, 128, 0, stream>>>(bestFg, bestBg, out);
}